// Round 5
// baseline (745.391 us; speedup 1.0000x reference)
//
#include <hip/hip_runtime.h>
#include <hip/hip_fp16.h>

#define NEG (-1e30f)

// B=2048, T=256, C=128, L=32, S=65.
// Block-per-row: 2048 blocks x 256 thr. 4 waves cooperate on phase 1
// (2 t-rows per wave-iter, 32 lanes/row, float4 loads). Raw row staged to
// LDS; label gather from LDS (no divergent global loads). Phase 2: DPP
// recursion on wave 0. LDS ~25.6KB -> 6 blocks/CU (75% occupancy).

__device__ __forceinline__ float dpp_shr1_neg(float x) {   // wave_shr:1, lane0<-NEG
    return __int_as_float(__builtin_amdgcn_update_dpp(
        __float_as_int(NEG), __float_as_int(x), 0x138, 0xF, 0xF, false));
}
__device__ __forceinline__ float dpp_add_xor1(float x) {   // quad_perm [1,0,3,2]
    return x + __int_as_float(__builtin_amdgcn_update_dpp(
        0, __float_as_int(x), 0xB1, 0xF, 0xF, true));
}
__device__ __forceinline__ float dpp_add_xor2(float x) {   // quad_perm [2,3,0,1]
    return x + __int_as_float(__builtin_amdgcn_update_dpp(
        0, __float_as_int(x), 0x4E, 0xF, 0xF, true));
}
__device__ __forceinline__ float dpp_add_hm(float x) {     // row_half_mirror (xor 4ish within 8)
    return x + __int_as_float(__builtin_amdgcn_update_dpp(
        0, __float_as_int(x), 0x141, 0xF, 0xF, true));
}
__device__ __forceinline__ float dpp_add_rm(float x) {     // row_mirror (within 16)
    return x + __int_as_float(__builtin_amdgcn_update_dpp(
        0, __float_as_int(x), 0x140, 0xF, 0xF, true));
}
__device__ __forceinline__ float dpp_even_bcast(float x) { // quad_perm [0,0,2,2]
    return __int_as_float(__builtin_amdgcn_update_dpp(
        0, __float_as_int(x), 0xA0, 0xF, 0xF, true));
}

__global__ __launch_bounds__(256, 6) void ctc_fused_kernel(
    const int* __restrict__ y_true,    // [2048,32]
    const float* __restrict__ y_pred,  // [2048,256,128]
    float* __restrict__ out)           // [2048]
{
    __shared__ __half lp[256][34];         // 17408 B: [t][j] j=0 blank, 1..32 labels
    __shared__ float  stage[4][2][2][128]; // 8192 B: [wave][half][parity][class]

    const int tid  = threadIdx.x;
    const int w    = tid >> 6;
    const int lane = tid & 63;
    const int h    = lane >> 5;   // half-wave: which of 2 rows this iter
    const int l    = lane & 31;   // lane within row
    const int b    = blockIdx.x;

    const float* __restrict__ Y   = y_pred + (size_t)b * 256 * 128;
    const int*   __restrict__ lab = y_true + b * 32;

    // class this lane gathers: j=l -> (l==0 ? blank : lab[l-1]); lane 0 also j=32
    const int myc   = (l == 0) ? 0 : lab[l - 1];
    const int myc32 = lab[31];

    // ---- Phase 1: softmax denom + LDS-staged gather; 2 rows per wave-iter ----
    #pragma unroll 2
    for (int it = 0; it < 32; ++it) {
        const int t = it * 8 + w * 2 + h;
        float* stg = &stage[w][h][it & 1][0];

        const float4 v = ((const float4*)(Y + (size_t)t * 128))[l];  // classes 4l..4l+3
        ((float4*)stg)[l] = v;                                       // raw row to LDS

        float se = __expf(v.x) + __expf(v.y) + __expf(v.z) + __expf(v.w);
        se = dpp_add_xor1(se);
        se = dpp_add_xor2(se);
        se = dpp_add_hm(se);
        se = dpp_add_rm(se);
        se += __shfl_xor(se, 16);          // cross the two 16-lane rows
        const float lse = __logf(se);

        lp[t][l] = __float2half(stg[myc] - lse);
        if (l == 0) lp[t][32] = __float2half(stg[myc32] - lse);
    }
    __syncthreads();

    // ---- Phase 2: forward recursion on wave 0; lane s = state; a64 in lane 63 ----
    if (w == 0) {
        const int s  = lane;
        const int hi = s >> 1;
        const int li = lab[hi];
        const int lm = (hi >= 1) ? lab[hi - 1] : 0;
        const bool can_skip = (s & 1) && (s >= 3) && (li != lm);
        const int  lpidx    = (s & 1) ? (1 + hi) : 0;
        const __half* P = &lp[0][0];

        float alpha = (s == 0) ? __half2float(P[0]) :
                      (s == 1) ? __half2float(P[1]) : NEG;
        float a64 = NEG;

        #pragma unroll 4
        for (int t = 1; t < 256; ++t) {
            const float x   = __half2float(P[t * 34 + lpidx]); // lpv for this lane
            const float lp0 = dpp_even_bcast(x);               // lp[t][0] from even lane

            // alpha[64] = logaddexp(a64, old alpha[63]) + lp(blank)
            float m2   = fmaxf(a64, alpha);
            float a64n = m2 + __logf(__expf(a64 - m2) + __expf(alpha - m2)) + lp0;

            float b1 = dpp_shr1_neg(alpha);    // alpha[s-1], NEG into s=0
            float b2 = dpp_shr1_neg(b1);       // alpha[s-2], NEG into s=0,1
            if (!can_skip) b2 = NEG;
            float m = fmaxf(fmaxf(alpha, b1), b2);
            alpha = m + __logf(__expf(alpha - m) + __expf(b1 - m) + __expf(b2 - m)) + x;
            a64 = a64n;
        }

        if (s == 63) {
            float m = fmaxf(alpha, a64);
            out[b] = -(m + __logf(__expf(alpha - m) + __expf(a64 - m)));
        }
    }
}

extern "C" void kernel_launch(void* const* d_in, const int* in_sizes, int n_in,
                              void* d_out, int out_size, void* d_ws, size_t ws_size,
                              hipStream_t stream) {
    const int*   y_true = (const int*)d_in[0];
    const float* y_pred = (const float*)d_in[1];
    float*       out    = (float*)d_out;
    ctc_fused_kernel<<<2048, 256, 0, stream>>>(y_true, y_pred, out);
}

// Round 6
// 367.042 us; speedup vs baseline: 2.0308x; 2.0308x over previous
//
#include <hip/hip_runtime.h>

// B=2048, T=256, C=128, L=32, S=65.
// One block (256 thr) per batch row. Chunked: 4 waves produce 64 timesteps of
// label probabilities into LDS, then wave 0 advances the scaled-prob forward
// recursion 64 steps. Prob space => no transcendentals on the serial chain;
// renorm by wave-max every 4 steps (worst per-step prob ~1e-7 -> 4-step
// product ~1e-28 >> fp32 min normal). LDS ~13KB -> 8 blocks/CU resident.

__device__ __forceinline__ float dpp_shr1_z(float x) {     // wave_shr:1, lane0<-0
    return __int_as_float(__builtin_amdgcn_update_dpp(
        0, __float_as_int(x), 0x138, 0xF, 0xF, false));
}
__device__ __forceinline__ float dpp_bcast_even(float x) { // quad_perm [0,0,2,2]
    return __int_as_float(__builtin_amdgcn_update_dpp(
        0, __float_as_int(x), 0xA0, 0xF, 0xF, true));
}
__device__ __forceinline__ float dpp_mv(float x, int ctrl_is_xor1, int which) {
    return 0.f; // unused placeholder
}
__device__ __forceinline__ float dpp_add_xor1(float x) {   // quad_perm [1,0,3,2]
    return x + __int_as_float(__builtin_amdgcn_update_dpp(
        0, __float_as_int(x), 0xB1, 0xF, 0xF, true));
}
__device__ __forceinline__ float dpp_add_xor2(float x) {   // quad_perm [2,3,0,1]
    return x + __int_as_float(__builtin_amdgcn_update_dpp(
        0, __float_as_int(x), 0x4E, 0xF, 0xF, true));
}
__device__ __forceinline__ float dpp_add_hm(float x) {     // row_half_mirror (8)
    return x + __int_as_float(__builtin_amdgcn_update_dpp(
        0, __float_as_int(x), 0x141, 0xF, 0xF, true));
}
__device__ __forceinline__ float dpp_add_rm(float x) {     // row_mirror (16)
    return x + __int_as_float(__builtin_amdgcn_update_dpp(
        0, __float_as_int(x), 0x140, 0xF, 0xF, true));
}
__device__ __forceinline__ float dpp_max_xor1(float x) {
    return fmaxf(x, __int_as_float(__builtin_amdgcn_update_dpp(
        0, __float_as_int(x), 0xB1, 0xF, 0xF, true)));
}
__device__ __forceinline__ float dpp_max_xor2(float x) {
    return fmaxf(x, __int_as_float(__builtin_amdgcn_update_dpp(
        0, __float_as_int(x), 0x4E, 0xF, 0xF, true)));
}
__device__ __forceinline__ float dpp_max_hm(float x) {
    return fmaxf(x, __int_as_float(__builtin_amdgcn_update_dpp(
        0, __float_as_int(x), 0x141, 0xF, 0xF, true)));
}
__device__ __forceinline__ float dpp_max_rm(float x) {
    return fmaxf(x, __int_as_float(__builtin_amdgcn_update_dpp(
        0, __float_as_int(x), 0x140, 0xF, 0xF, true)));
}

__global__ __launch_bounds__(256) void ctc_fused_kernel(
    const int* __restrict__ y_true,    // [2048,32]
    const float* __restrict__ y_pred,  // [2048,256,128]
    float* __restrict__ out)           // [2048]
{
    __shared__ float pstage[8][128];   // 4 KB: per half-wave exp'ed row
    __shared__ float pbuf[64][34];     // 8.7 KB: chunk of label probs [t_local][j]
    __shared__ int   labs[32];

    const int tid  = threadIdx.x;
    const int w    = tid >> 6;
    const int lane = tid & 63;
    const int h    = lane >> 5;   // which of the wave's 2 rows this iter
    const int l    = lane & 31;   // lane within row
    const int b    = blockIdx.x;

    if (tid < 32) labs[tid] = y_true[b * 32 + tid];
    __syncthreads();

    const float* __restrict__ Y = y_pred + (size_t)b * 256 * 128;

    // phase-1 per-lane gather class: j=l (j=0 blank, j>=1 -> label j-1)
    const int myc   = (l == 0) ? 0 : labs[l - 1];
    const int myc32 = labs[31];

    // phase-2 per-lane constants (lane s = state 0..63; state 64 in lane 63)
    const int s  = lane;
    const int hi = s >> 1;
    const int li = labs[hi];
    const int lm = (hi >= 1) ? labs[hi - 1] : 0;
    const bool can_skip = (s & 1) && (s >= 3) && (li != lm);
    const int  lpidx    = (s & 1) ? (1 + hi) : 0;

    float alpha = 0.f, a64 = 0.f, shift2 = 0.f;

    float* stg = &pstage[w * 2 + h][0];

    for (int c = 0; c < 4; ++c) {
        // ---- produce probs for t in [c*64, c*64+64): 8 rows per iter ----
        for (int it = 0; it < 8; ++it) {
            const int tl = it * 8 + w * 2 + h;
            const int t  = c * 64 + tl;
            const float4 v = ((const float4*)(Y + (size_t)t * 128))[l];
            const float e0 = __expf(v.x), e1 = __expf(v.y);
            const float e2 = __expf(v.z), e3 = __expf(v.w);
            ((float4*)stg)[l] = make_float4(e0, e1, e2, e3);
            float se = (e0 + e1) + (e2 + e3);
            se = dpp_add_xor1(se);
            se = dpp_add_xor2(se);
            se = dpp_add_hm(se);
            se = dpp_add_rm(se);
            se += __shfl_xor(se, 16);          // join the two 16-lane rows
            const float r = __builtin_amdgcn_rcpf(se);
            pbuf[tl][l] = stg[myc] * r;
            if (l == 0) pbuf[tl][32] = stg[myc32] * r;
        }
        __syncthreads();

        // ---- consume 64 steps on wave 0 (scaled-prob recursion) ----
        if (w == 0) {
            int tl0 = 0;
            if (c == 0) {
                alpha = (s == 0) ? pbuf[0][0] : (s == 1) ? pbuf[0][1] : 0.f;
                tl0 = 1;
            }
            #pragma unroll 4
            for (int tl = tl0; tl < 64; ++tl) {
                const float x  = pbuf[tl][lpidx];     // p[t][state s]
                const float p0 = dpp_bcast_even(x);   // p[t][blank]
                const float a64n = (a64 + alpha) * p0; // lane 63: state 64
                float b1 = dpp_shr1_z(alpha);          // alpha[s-1]
                float b2 = dpp_shr1_z(b1);             // alpha[s-2]
                b2 = can_skip ? b2 : 0.f;
                alpha = (alpha + b1 + b2) * x;
                a64 = a64n;
                if ((tl & 3) == 3) {                   // renorm every 4 steps
                    float m = alpha;
                    m = dpp_max_xor1(m); m = dpp_max_xor2(m);
                    m = dpp_max_hm(m);   m = dpp_max_rm(m);
                    m = fmaxf(m, __shfl_xor(m, 16));
                    m = fmaxf(m, __shfl_xor(m, 32));
                    const float rr = __builtin_amdgcn_rcpf(m);
                    alpha *= rr;
                    a64   *= rr;
                    shift2 += __log2f(m);
                }
            }
        }
        __syncthreads();
    }

    if (w == 0 && s == 63) {
        // loss = -ln(alpha[63] + alpha[64]) - shift
        out[b] = -((__log2f(alpha + a64) + shift2) * 0.6931471805599453f);
    }
}

extern "C" void kernel_launch(void* const* d_in, const int* in_sizes, int n_in,
                              void* d_out, int out_size, void* d_ws, size_t ws_size,
                              hipStream_t stream) {
    const int*   y_true = (const int*)d_in[0];
    const float* y_pred = (const float*)d_in[1];
    float*       out    = (float*)d_out;
    ctc_fused_kernel<<<2048, 256, 0, stream>>>(y_true, y_pred, out);
}